// Round 1
// baseline (149845.349 us; speedup 1.0000x reference)
//
#include <hip/hip_runtime.h>
#include <hip/hip_bf16.h>
#include <stdint.h>

#define NB 256   // batch
#define NT 512   // time
#define NV 128   // vocab
#define NE 64    // embed
#define NH 256   // hidden

// ---------------- helpers ----------------
__device__ __forceinline__ float lo_bf(unsigned u){ return __uint_as_float(u << 16); }
__device__ __forceinline__ float hi_bf(unsigned u){ return __uint_as_float(u & 0xffff0000u); }
__device__ __forceinline__ unsigned short f2us(float f){
  unsigned u = __float_as_uint(f);
  unsigned r = u + 0x7fffu + ((u >> 16) & 1u);
  return (unsigned short)(r >> 16);
}
__device__ __forceinline__ float sigm(float x){
  return __builtin_amdgcn_rcpf(1.f + __expf(-x));
}
__device__ __forceinline__ float ftanh(float xx){
  float a = fabsf(xx);
  a = fminf(a, 9.f);
  float e = __expf(2.f * a);
  float r = __builtin_amdgcn_rcpf(e + 1.f);
  float t = (e - 1.f) * r;
  return copysignf(t, xx);
}

// 16-workgroup group barrier (monotonic counter, device scope)
__device__ __forceinline__ void groupbar(unsigned* c, unsigned target){
  __threadfence();
  __syncthreads();
  if (threadIdx.x == 0){
    __hip_atomic_fetch_add(c, 1u, __ATOMIC_RELEASE, __HIP_MEMORY_SCOPE_AGENT);
    while (__hip_atomic_load(c, __ATOMIC_ACQUIRE, __HIP_MEMORY_SCOPE_AGENT) < target)
      __builtin_amdgcn_s_sleep(2);
  }
  __syncthreads();
  __threadfence();
}

// ---------------- encoder (persistent, 512 steps, fuses keys_proj) ----------------
// grid 256 WGs: (gb = blk>>4) owns rows [gb*16,+16), (gc = blk&15) owns h-cols [gc*16,+16)
__global__ __launch_bounds__(256, 1)
void enc_kernel(const int* __restrict__ x, const float* __restrict__ emb,
                const float* __restrict__ Wih, const float* __restrict__ Whh,
                const float* __restrict__ bih, const float* __restrict__ bhh,
                const float* __restrict__ Wk,
                unsigned short* __restrict__ enc_out, unsigned short* __restrict__ keys,
                float* __restrict__ g_h, float* __restrict__ g_c,
                unsigned* __restrict__ ctrs)
{
  const int tid = threadIdx.x;
  const int blk = blockIdx.x;
  const int gb = blk >> 4, gc = blk & 15;
  const int r0 = gb * 16, c0 = gc * 16;

  extern __shared__ char smem[];
  float* sWi   = (float*)smem;                 // [64][64]  k-major: sWi[k*64+cj]
  float* sWh   = sWi  + 64*64;                 // [256][64]
  float* sWk   = sWh  + 256*64;                // [16][260]
  float* sBias = sWk  + 16*260;                // [64]
  float* sH    = sBias + 64;                   // [16][256]
  float* sXe   = sH   + 16*256;                // [16][64]
  float* sG    = sXe  + 16*64;                 // [64][17]
  uint8_t* sXi = (uint8_t*)(sG + 64*17);       // [16][512]

  for (int i = tid; i < 64*64; i += 256){
    int cj = i & 63, k = i >> 6;
    int grow = ((cj >> 4) * NH) + c0 + (cj & 15);
    sWi[k*64 + cj] = Wih[grow*NE + k];
  }
  for (int i = tid; i < 256*64; i += 256){
    int cj = i & 63, k = i >> 6;
    int grow = ((cj >> 4) * NH) + c0 + (cj & 15);
    sWh[k*64 + cj] = Whh[grow*NH + k];
  }
  if (tid < 64){
    int grow = ((tid >> 4) * NH) + c0 + (tid & 15);
    sBias[tid] = bih[grow] + bhh[grow];
  }
  for (int i = tid; i < 16*256; i += 256){
    int qc = i >> 8, k = i & 255;
    sWk[qc*260 + k] = Wk[(c0 + qc)*NH + k];
  }
  for (int i = tid; i < 16*512; i += 256){
    int rr = i >> 9;
    sXi[i] = (uint8_t)x[(r0 + rr)*NT + (i & 511)];
  }
  for (int i = tid; i < 16*256; i += 256) sH[i] = 0.f;
  __syncthreads();

  const int r  = tid >> 4;
  const int cq = tid & 15;
  float creg = 0.f;
  unsigned* ctr = ctrs + gb*16;

  for (int t = 0; t < NT; ++t){
    // keys_proj for step t-1 (sH currently holds h_{t-1})
    if (t > 0){
      float kv = 0.f;
      const float4* hv = (const float4*)(sH + r*256);
      const float4* wv = (const float4*)(sWk + cq*260);
      #pragma unroll 8
      for (int k4 = 0; k4 < 64; ++k4){
        float4 a = hv[k4], w = wv[k4];
        kv += a.x*w.x + a.y*w.y + a.z*w.z + a.w*w.w;
      }
      keys[((size_t)(r0 + r)*NT + (t-1))*NH + c0 + cq] = f2us(kv);
    }
    // gather x_t embedding
    {
      int idx = sXi[r*512 + t];
      float4 ev = *(const float4*)(emb + idx*NE + cq*4);
      *(float4*)(sXe + r*64 + cq*4) = ev;
    }
    __syncthreads();
    // gates: thread (r, cq) -> gate cols cq*4..cq*4+3 (of 64)
    {
      float4 acc = *(float4*)&sBias[cq*4];
      #pragma unroll 8
      for (int k = 0; k < NE; ++k){
        float a = sXe[r*64 + k];
        float4 w = *(const float4*)(sWi + k*64 + cq*4);
        acc.x += a*w.x; acc.y += a*w.y; acc.z += a*w.z; acc.w += a*w.w;
      }
      #pragma unroll 8
      for (int k = 0; k < NH; ++k){
        float a = sH[r*256 + k];
        float4 w = *(const float4*)(sWh + k*64 + cq*4);
        acc.x += a*w.x; acc.y += a*w.y; acc.z += a*w.z; acc.w += a*w.w;
      }
      sG[(cq*4 + 0)*17 + r] = acc.x;
      sG[(cq*4 + 1)*17 + r] = acc.y;
      sG[(cq*4 + 2)*17 + r] = acc.z;
      sG[(cq*4 + 3)*17 + r] = acc.w;
    }
    __syncthreads();
    // cell update: thread (r, cq) owns cell (r0+r, c0+cq)
    {
      float gi = sigm (sG[( 0 + cq)*17 + r]);
      float gf = sigm (sG[(16 + cq)*17 + r]);
      float gg = ftanh(sG[(32 + cq)*17 + r]);
      float go = sigm (sG[(48 + cq)*17 + r]);
      float cn = gf*creg + gi*gg;
      float hn = go*ftanh(cn);
      creg = cn;
      g_h[((t+1)&1)*NB*NH + (r0+r)*NH + c0 + cq] = hn;
      enc_out[((size_t)(r0+r)*NT + t)*NH + c0 + cq] = f2us(hn);
    }
    groupbar(ctr, (unsigned)(16*(t+1)));
    // reload full h rows for next step
    {
      const float4* src = (const float4*)(g_h + ((t+1)&1)*NB*NH + r0*NH);
      float4* dst = (float4*)sH;
      #pragma unroll 4
      for (int i = tid; i < 1024; i += 256) dst[i] = src[i];
    }
    __syncthreads();
  }
  // keys for final step from sH = h_{511}
  {
    float kv = 0.f;
    const float4* hv = (const float4*)(sH + r*256);
    const float4* wv = (const float4*)(sWk + cq*260);
    #pragma unroll 8
    for (int k4 = 0; k4 < 64; ++k4){
      float4 a = hv[k4], w = wv[k4];
      kv += a.x*w.x + a.y*w.y + a.z*w.z + a.w*w.w;
    }
    keys[((size_t)(r0 + r)*NT + (NT-1))*NH + c0 + cq] = f2us(kv);
  }
  g_c[(r0 + r)*NH + c0 + cq] = creg;
}

// ---------------- decoder (persistent, 512 steps, 3 group-barriers/step) ----------------
__global__ __launch_bounds__(256, 1)
void dec_kernel(const int* __restrict__ x, const float* __restrict__ emb,
                const float* __restrict__ Wq, const float* __restrict__ vvec,
                const float* __restrict__ Wih, const float* __restrict__ Whh,
                const float* __restrict__ bih, const float* __restrict__ bhh,
                const float* __restrict__ Wfc, const float* __restrict__ bfc,
                const unsigned short* __restrict__ enc_out, const unsigned short* __restrict__ keys,
                float* __restrict__ g_h, float* __restrict__ g_c,
                float* __restrict__ g_q, float* __restrict__ g_ctx,
                float* __restrict__ logits, float* __restrict__ out_h, float* __restrict__ out_c,
                unsigned* __restrict__ ctrs)
{
  const int tid = threadIdx.x;
  const int blk = blockIdx.x;
  const int gb = blk >> 4, gc = blk & 15;
  const int r0 = gb*16, c0 = gc*16;
  const int ra = blk;              // this WG's attention row (= r0 + gc)

  extern __shared__ char smem[];
  float* sWq  = (float*)smem;            // [16][260]
  float* sWfc = sWq  + 16*260;           // [8][260]
  float* sV   = sWfc + 8*260;            // [256]
  float* sBias= sV + 256;                // [64]
  float* sBfc = sBias + 64;              // [8]
  float* sQ   = sBfc + 8;                // [256]
  float* sRed = sQ + 256;                // [64]
  float* sWp  = sRed + 64;               // [512]
  float* sH   = sWp + 512;               // [16][256]
  float* sCtx = sH + 16*256;             // [16][256]
  float* sXe  = sCtx + 16*256;           // [16][64]
  float* sG   = sXe + 16*64;             // [64][17]
  float* sCp  = sXe;                     // overlay: [8][256] ctx partials (xe+G region)
  unsigned short* sWihd = (unsigned short*)(sG + 64*17);   // [320][64] bf16
  unsigned short* sWhhd = sWihd + 320*64;                  // [256][64] bf16
  uint8_t* sXi = (uint8_t*)(sWhhd + 256*64);               // [16][512]

  for (int i = tid; i < 16*256; i += 256){
    int qc = i >> 8, k = i & 255;
    sWq[qc*260 + k] = Wq[(c0 + qc)*NH + k];
  }
  for (int i = tid; i < 8*256; i += 256){
    int vc = i >> 8, k = i & 255;
    sWfc[vc*260 + k] = Wfc[(gc*8 + vc)*NH + k];
  }
  if (tid < 256) sV[tid] = vvec[tid];
  if (tid < 64){
    int grow = ((tid >> 4)*NH) + c0 + (tid & 15);
    sBias[tid] = bih[grow] + bhh[grow];
  }
  if (tid < 8) sBfc[tid] = bfc[gc*8 + tid];
  for (int i = tid; i < 320*64; i += 256){
    int cj = i & 63, k = i >> 6;
    int grow = ((cj >> 4)*NH) + c0 + (cj & 15);
    sWihd[k*64 + cj] = f2us(Wih[grow*320 + k]);
  }
  for (int i = tid; i < 256*64; i += 256){
    int cj = i & 63, k = i >> 6;
    int grow = ((cj >> 4)*NH) + c0 + (cj & 15);
    sWhhd[k*64 + cj] = f2us(Whh[grow*NH + k]);
  }
  for (int i = tid; i < 16*512; i += 256){
    int rr = i >> 9;
    sXi[i] = (uint8_t)x[(r0 + rr)*NT + (i & 511)];
  }
  const int r  = tid >> 4;
  const int cq = tid & 15;
  float creg = g_c[(r0 + r)*NH + c0 + cq];
  float hlast = 0.f;
  unsigned* ctr = ctrs + 256 + gb*16;
  __syncthreads();

  for (int t = 0; t < NT; ++t){
    // ---- Phase Q: load h_{t-1}, q projection, logits[t-1] ----
    {
      const float4* src = (const float4*)(g_h + r0*NH);
      float4* dst = (float4*)sH;
      #pragma unroll 4
      for (int i = tid; i < 1024; i += 256) dst[i] = src[i];
    }
    __syncthreads();
    {
      float qv = 0.f;
      const float4* hv = (const float4*)(sH + r*256);
      const float4* wv = (const float4*)(sWq + cq*260);
      #pragma unroll 8
      for (int k4 = 0; k4 < 64; ++k4){
        float4 a = hv[k4], w = wv[k4];
        qv += a.x*w.x + a.y*w.y + a.z*w.z + a.w*w.w;
      }
      g_q[(r0 + r)*NH + c0 + cq] = qv;
    }
    if (t > 0 && cq < 8){
      float lv = sBfc[cq];
      const float4* hv = (const float4*)(sH + r*256);
      const float4* wv = (const float4*)(sWfc + cq*260);
      #pragma unroll 8
      for (int k4 = 0; k4 < 64; ++k4){
        float4 a = hv[k4], w = wv[k4];
        lv += a.x*w.x + a.y*w.y + a.z*w.z + a.w*w.w;
      }
      logits[((size_t)(r0 + r)*NT + (t-1))*NV + gc*8 + cq] = lv;
    }
    groupbar(ctr, (unsigned)(48*t + 16));

    // ---- Phase A: attention for row ra ----
    sQ[tid] = g_q[ra*NH + tid];
    __syncthreads();
    {
      #pragma unroll
      for (int j = 0; j < 2; ++j){
        int s = tid + j*256;
        float acc = 0.f;
        const uint4* kp = (const uint4*)(keys + ((size_t)ra*NT + s)*NH);
        #pragma unroll 4
        for (int k8 = 0; k8 < 32; ++k8){
          uint4 u = kp[k8];
          int kb = k8*8;
          acc += sV[kb+0]*ftanh(sQ[kb+0] + lo_bf(u.x));
          acc += sV[kb+1]*ftanh(sQ[kb+1] + hi_bf(u.x));
          acc += sV[kb+2]*ftanh(sQ[kb+2] + lo_bf(u.y));
          acc += sV[kb+3]*ftanh(sQ[kb+3] + hi_bf(u.y));
          acc += sV[kb+4]*ftanh(sQ[kb+4] + lo_bf(u.z));
          acc += sV[kb+5]*ftanh(sQ[kb+5] + hi_bf(u.z));
          acc += sV[kb+6]*ftanh(sQ[kb+6] + lo_bf(u.w));
          acc += sV[kb+7]*ftanh(sQ[kb+7] + hi_bf(u.w));
        }
        bool pad = (sXi[gc*512 + s] == 0);
        sWp[s] = pad ? 0.f : __expf(acc);
      }
    }
    __syncthreads();
    if (tid < 64){
      float sum = 0.f;
      #pragma unroll
      for (int i2 = tid; i2 < 512; i2 += 64) sum += sWp[i2];
      #pragma unroll
      for (int off = 32; off > 0; off >>= 1) sum += __shfl_down(sum, off, 64);
      if (tid == 0) sRed[0] = sum;
    }
    __syncthreads();
    {
      float d = sRed[0];
      float rden = (d > 0.f) ? (1.f / d) : 0.f;
      const int sc  = tid >> 5;         // s-chunk 0..7 (64 positions each)
      const int cg8 = (tid & 31) * 8;   // col base 0..248
      float a8[8];
      #pragma unroll
      for (int m = 0; m < 8; ++m) a8[m] = 0.f;
      const uint4* ep = (const uint4*)(enc_out + ((size_t)ra*NT + sc*64)*NH + cg8);
      #pragma unroll 4
      for (int s64 = 0; s64 < 64; ++s64){
        float w = sWp[sc*64 + s64];
        uint4 u = ep[(size_t)s64*32];
        a8[0] += w*lo_bf(u.x); a8[1] += w*hi_bf(u.x);
        a8[2] += w*lo_bf(u.y); a8[3] += w*hi_bf(u.y);
        a8[4] += w*lo_bf(u.z); a8[5] += w*hi_bf(u.z);
        a8[6] += w*lo_bf(u.w); a8[7] += w*hi_bf(u.w);
      }
      *(float4*)(sCp + sc*256 + cg8)     = make_float4(a8[0],a8[1],a8[2],a8[3]);
      *(float4*)(sCp + sc*256 + cg8 + 4) = make_float4(a8[4],a8[5],a8[6],a8[7]);
      __syncthreads();
      float csum = 0.f;
      #pragma unroll
      for (int p8 = 0; p8 < 8; ++p8) csum += sCp[p8*256 + tid];
      g_ctx[ra*NH + tid] = csum * rden;
    }
    groupbar(ctr, (unsigned)(48*t + 32));

    // ---- Phase L: LSTM cell (input = [emb_t | ctx]) ----
    {
      const float4* src = (const float4*)(g_ctx + r0*NH);
      float4* dst = (float4*)sCtx;
      #pragma unroll 4
      for (int i = tid; i < 1024; i += 256) dst[i] = src[i];
      int idx = sXi[r*512 + t];
      float4 ev = *(const float4*)(emb + idx*NE + cq*4);
      *(float4*)(sXe + r*64 + cq*4) = ev;
    }
    __syncthreads();
    {
      float4 acc = *(float4*)&sBias[cq*4];
      #pragma unroll 8
      for (int k = 0; k < NE; ++k){
        float a = sXe[r*64 + k];
        uint2 u = *(const uint2*)(sWihd + k*64 + cq*4);
        acc.x += a*lo_bf(u.x); acc.y += a*hi_bf(u.x);
        acc.z += a*lo_bf(u.y); acc.w += a*hi_bf(u.y);
      }
      #pragma unroll 8
      for (int k = 0; k < NH; ++k){
        float a = sCtx[r*256 + k];
        uint2 u = *(const uint2*)(sWihd + (64+k)*64 + cq*4);
        acc.x += a*lo_bf(u.x); acc.y += a*hi_bf(u.x);
        acc.z += a*lo_bf(u.y); acc.w += a*hi_bf(u.y);
      }
      #pragma unroll 8
      for (int k = 0; k < NH; ++k){
        float a = sH[r*256 + k];
        uint2 u = *(const uint2*)(sWhhd + k*64 + cq*4);
        acc.x += a*lo_bf(u.x); acc.y += a*hi_bf(u.x);
        acc.z += a*lo_bf(u.y); acc.w += a*hi_bf(u.y);
      }
      sG[(cq*4+0)*17 + r] = acc.x;
      sG[(cq*4+1)*17 + r] = acc.y;
      sG[(cq*4+2)*17 + r] = acc.z;
      sG[(cq*4+3)*17 + r] = acc.w;
    }
    __syncthreads();
    {
      float gi = sigm (sG[( 0 + cq)*17 + r]);
      float gf = sigm (sG[(16 + cq)*17 + r]);
      float gg = ftanh(sG[(32 + cq)*17 + r]);
      float go = sigm (sG[(48 + cq)*17 + r]);
      float cn = gf*creg + gi*gg;
      hlast = go*ftanh(cn);
      creg = cn;
      g_h[(r0+r)*NH + c0 + cq] = hlast;
    }
    groupbar(ctr, (unsigned)(48*t + 48));
  }

  // final logits (t = 511) + h_f, c_f
  {
    const float4* src = (const float4*)(g_h + r0*NH);
    float4* dst = (float4*)sH;
    #pragma unroll 4
    for (int i = tid; i < 1024; i += 256) dst[i] = src[i];
  }
  __syncthreads();
  if (cq < 8){
    float lv = sBfc[cq];
    const float4* hv = (const float4*)(sH + r*256);
    const float4* wv = (const float4*)(sWfc + cq*260);
    #pragma unroll 8
    for (int k4 = 0; k4 < 64; ++k4){
      float4 a = hv[k4], w = wv[k4];
      lv += a.x*w.x + a.y*w.y + a.z*w.z + a.w*w.w;
    }
    logits[((size_t)(r0 + r)*NT + (NT-1))*NV + gc*8 + cq] = lv;
  }
  out_h[(r0 + r)*NH + c0 + cq] = hlast;
  out_c[(r0 + r)*NH + c0 + cq] = creg;
}

// ---------------- launcher ----------------
extern "C" void kernel_launch(void* const* d_in, const int* in_sizes, int n_in,
                              void* d_out, int out_size, void* d_ws, size_t ws_size,
                              hipStream_t stream)
{
  (void)in_sizes; (void)n_in; (void)out_size; (void)ws_size;
  const int*   x    = (const int*)  d_in[0];
  const float* emb  = (const float*)d_in[1];
  const float* Wihe = (const float*)d_in[2];
  const float* Whhe = (const float*)d_in[3];
  const float* bihe = (const float*)d_in[4];
  const float* bhhe = (const float*)d_in[5];
  const float* Wq   = (const float*)d_in[6];
  const float* Wk   = (const float*)d_in[7];
  const float* vv   = (const float*)d_in[8];
  const float* Wihd = (const float*)d_in[9];
  const float* Whhd = (const float*)d_in[10];
  const float* bihd = (const float*)d_in[11];
  const float* bhhd = (const float*)d_in[12];
  const float* Wfc  = (const float*)d_in[13];
  const float* bfc  = (const float*)d_in[14];

  char* ws = (char*)d_ws;
  unsigned* ctrs = (unsigned*)ws;                                 // 8 KB
  unsigned short* enc  = (unsigned short*)(ws + 8192);            // 64 MB (bf16)
  unsigned short* keys = (unsigned short*)(ws + 8192 + 67108864); // 64 MB (bf16)
  float* g_h  = (float*)(ws + 8192 + 2*67108864);                 // 2 * B*H
  float* g_c  = g_h + 2*NB*NH;
  float* g_q  = g_c + NB*NH;
  float* g_ctx= g_q + NB*NH;

  float* out_logits = (float*)d_out;
  float* out_h = out_logits + (size_t)NB*NT*NV;
  float* out_c = out_h + NB*NH;

  hipMemsetAsync(ctrs, 0, 8192, stream);

  const size_t smem_enc = (size_t)(64*64 + 256*64 + 16*260 + 64 + 16*256 + 16*64 + 64*17)*4 + 16*512;
  const size_t smem_dec = (size_t)(16*260 + 8*260 + 256 + 64 + 8 + 256 + 64 + 512
                                   + 16*256 + 16*256 + 16*64 + 64*17)*4
                          + (size_t)(320*64 + 256*64)*2 + 16*512;

  enc_kernel<<<dim3(256), dim3(256), smem_enc, stream>>>(
      x, emb, Wihe, Whhe, bihe, bhhe, Wk, enc, keys, g_h, g_c, ctrs);
  dec_kernel<<<dim3(256), dim3(256), smem_dec, stream>>>(
      x, emb, Wq, vv, Wihd, Whhd, bihd, bhhd, Wfc, bfc,
      enc, keys, g_h, g_c, g_q, g_ctx, out_logits, out_h, out_c, ctrs);
}